// Round 5
// baseline (325.737 us; speedup 1.0000x reference)
//
#include <hip/hip_runtime.h>

#define NROI 1000
#define NCLS 81
#define NB   8
#define NLANE (NB*NCLS)        // 648
#define MAXM 1024
#define MAXKEEP 200
#define SCORE_T 0.5f
#define IOU_T 0.5f
#define HBITS 13
#define HSIZE (1<<HBITS)       // 8192 buckets
#define SCAP 1024

typedef unsigned long long u64;
typedef unsigned int u32;

// --- exact-order helpers (no FMA contraction; must match f32 numpy reference) ---

__device__ __forceinline__ void decode_box(const float* __restrict__ roi,
                                           const float* __restrict__ dl,
                                           float& oy1, float& ox1,
                                           float& oy2, float& ox2) {
#pragma clang fp contract(off)
  float y1 = roi[0], x1 = roi[1], y2 = roi[2], x2 = roi[3];
  float h = y2 - y1;
  float w = x2 - x1;
  float cy = y1 + 0.5f * h;
  float cx = x1 + 0.5f * w;
  float d0 = dl[0] * 0.1f;
  float d1 = dl[1] * 0.1f;
  float d2 = dl[2] * 0.2f;
  float d3 = dl[3] * 0.2f;
  float ncy = d0 * h + cy;
  float ncx = d1 * w + cx;
  float nh = expf(d2) * h;
  float nw = expf(d3) * w;
  oy1 = ncy - 0.5f * nh;
  ox1 = ncx - 0.5f * nw;
  oy2 = ncy + 0.5f * nh;
  ox2 = ncx + 0.5f * nw;
}

__device__ __forceinline__ float area_f(float4 bx) {
#pragma clang fp contract(off)
  return (bx.z - bx.x) * (bx.w - bx.y);
}

// EXACT equivalent of: fl32(inter/den) > 0.5 (round-nearest-even).
// fl(q) > 0.5  <=>  q_real > 0.5 + 2^-25  <=>  inter > (0.5+2^-25)*den,
// and (0.5+2^-25)*den is exact in double (25b x 24b mantissas < 53b).
__device__ __forceinline__ bool hit_f(float4 bi, float ia, float4 bj, float ja) {
#pragma clang fp contract(off)
  float yy1 = fmaxf(bi.x, bj.x);
  float xx1 = fmaxf(bi.y, bj.y);
  float yy2 = fminf(bi.z, bj.z);
  float xx2 = fminf(bi.w, bj.w);
  float ih = fmaxf(yy2 - yy1, 0.0f);
  float iw = fmaxf(xx2 - xx1, 0.0f);
  float inter = ih * iw;
  float den = ia + ja;
  den = den - inter;
  den = den + 1e-8f;
  return (double)inter > (0.5 + 0x1p-25) * (double)den;
}

// key packing: [63:32] score bits, [31:15] (131071-flat) so lower flat wins,
//              [14:5] n (payload only), [4:0] zero. Empty slot = 0.
__device__ __forceinline__ u64 pack_key(u32 sbits, int flat, int n) {
  return ((u64)sbits << 32) | ((u64)(131071 - flat) << 15) | ((u64)n << 5);
}

// --- kernel 1: background rows (argmax over classes == 0), wave per row ---
__global__ __launch_bounds__(256) void bg_kernel(const float* __restrict__ probs,
                                                 int* __restrict__ bg) {
  int row = blockIdx.x * 4 + (threadIdx.x >> 6);
  int lane = threadIdx.x & 63;
  if (row >= NB * NROI) return;
  const float* p = probs + (size_t)row * NCLS;
  float m = -1e30f;
  for (int idx = 1 + lane; idx < NCLS; idx += 64) m = fmaxf(m, p[idx]);
  for (int off = 32; off; off >>= 1) m = fmaxf(m, __shfl_xor(m, off));
  if (lane == 0) bg[row] = (p[0] >= m) ? 1 : 0;  // argmax==0 iff p0 >= all others
}

// --- kernel 2 (fused): gather + rank-sort + decode + bulk-mask greedy NMS + compact ---
__global__ __launch_bounds__(256) void gather_nms_kernel(
    const float* __restrict__ roi, const float* __restrict__ deltas,
    const float* __restrict__ probs, const int* __restrict__ bg,
    u64* __restrict__ sorted_key, int* __restrict__ keep_count,
    u64* __restrict__ lane_key) {
  int lane = blockIdx.x;               // 0..647
  int b = lane / NCLS, c = lane % NCLS;
  int tid = threadIdx.x;
  int w = tid >> 6, l = tid & 63;

  // aliased smem: [0,16K) skey(8K, dead after sort) -> sbox(16K)
  //               [16K,24K) skey2 (sorted keys) -> hmask
  __shared__ alignas(16) char smem[24576];
  float4* sbox  = (float4*)smem;
  u64*    skey  = (u64*)smem;
  u64*    skey2 = (u64*)(smem + 16384);
  u64*    hmask = skey2;
  __shared__ u64 keepmask[16];
  __shared__ u64 chunk_kept;
  __shared__ int scount, segbase[16];

  if (tid == 0) scount = 0;
  __syncthreads();

  // --- gather: score > 0.5 && !bg (ballot-aggregated append; M <= 1000) ---
  for (int base_n = 0; base_n < NROI; base_n += 256) {
    int n = base_n + tid;
    bool cand = false;
    float s = 0.0f;
    if (n < NROI) {
      int row = b * NROI + n;
      s = probs[(size_t)row * NCLS + c];
      cand = (s > SCORE_T) && (bg[row] == 0);
    }
    u64 bal = __ballot(cand);
    int wbase = 0;
    if (l == 0) wbase = atomicAdd(&scount, (int)__popcll(bal));
    wbase = __shfl(wbase, 0);
    if (cand) {
      int off = (int)__popcll(bal & ((1ull << l) - 1ull));
      skey[wbase + off] = ((u64)__float_as_uint(s) << 32) | (u64)(0xFFFFFFFFu - (u32)n);
    }
  }
  __syncthreads();
  int M = scount;

  // --- rank sort: keys unique -> rank is a permutation ---
  u64 myk0 = (tid       < M) ? skey[tid      ] : 0ull;
  u64 myk1 = (tid + 256 < M) ? skey[tid + 256] : 0ull;
  u64 myk2 = (tid + 512 < M) ? skey[tid + 512] : 0ull;
  u64 myk3 = (tid + 768 < M) ? skey[tid + 768] : 0ull;
  int r0 = 0, r1 = 0, r2 = 0, r3 = 0;
  for (int q = 0; q < M; ++q) {        // broadcast LDS read, conflict-free
    u64 kq = skey[q];
    r0 += kq > myk0; r1 += kq > myk1; r2 += kq > myk2; r3 += kq > myk3;
  }
  if (tid < 16) {                       // init keep bitmask: bits p < M set
    int rem = M - (tid << 6);
    keepmask[tid] = (rem >= 64) ? ~0ull : ((rem <= 0) ? 0ull : ((1ull << rem) - 1ull));
  }
  size_t gbase = (size_t)lane << 10;
  if (tid       < M) { skey2[r0] = myk0; sorted_key[gbase + r0] = myk0; }
  if (tid + 256 < M) { skey2[r1] = myk1; sorted_key[gbase + r1] = myk1; }
  if (tid + 512 < M) { skey2[r2] = myk2; sorted_key[gbase + r2] = myk2; }
  if (tid + 768 < M) { skey2[r3] = myk3; sorted_key[gbase + r3] = myk3; }
  __syncthreads();   // skey reads done; skey2 ready

  // --- decode sorted candidates into sbox (overwrites dead skey region) ---
  for (int p = tid; p < M; p += 256) {
    u64 k = skey2[p];
    u32 n = 0xFFFFFFFFu - (u32)(k & 0xFFFFFFFFull);
    int row = b * NROI + (int)n;
    float by1, bx1, by2, bx2;
    decode_box(roi + (size_t)row * 4, deltas + ((size_t)row * NCLS + c) * 4,
               by1, bx1, by2, bx2);
    sbox[p] = make_float4(by1, bx1, by2, bx2);
  }

  // --- chunked greedy NMS: bulk hit-mask map (4-way j-blocked) + ballot resolve ---
  int nchunks = (M + 63) >> 6;
  for (int ck = 0; ck < nchunks; ++ck) {
    int start = ck << 6;
    __syncthreads();   // A: decode done (ck=0) / prev step3 done; hmask safe to write

    {  // step 1: hit masks for all j >= start vs chunk boxes
      int j0 = start + tid, j1 = j0 + 256, j2 = j0 + 512, j3 = j0 + 768;
      u64 w0 = (j0 < M) ? keepmask[j0 >> 6] : 0ull;
      u64 w1 = (j1 < M) ? keepmask[j1 >> 6] : 0ull;
      u64 w2 = (j2 < M) ? keepmask[j2 >> 6] : 0ull;
      u64 w3 = (j3 < M) ? keepmask[j3 >> 6] : 0ull;
      if ((w0 | w1 | w2 | w3) != 0ull) {   // wave-uniform dead-skip
        float4 bj0 = sbox[j0 < MAXM ? j0 : 0];
        float4 bj1 = sbox[j1 < MAXM ? j1 : 0];
        float4 bj2 = sbox[j2 < MAXM ? j2 : 0];
        float4 bj3 = sbox[j3 < MAXM ? j3 : 0];
        float ja0 = area_f(bj0), ja1 = area_f(bj1);
        float ja2 = area_f(bj2), ja3 = area_f(bj3);
        u64 h0 = 0, h1 = 0, h2 = 0, h3 = 0;
#pragma unroll 8
        for (int i = 0; i < 64; ++i) {
          float4 bi = sbox[start + i];   // garbage beyond M: provably masked later
          float ia = area_f(bi);
          if (hit_f(bi, ia, bj0, ja0)) h0 |= (1ull << i);
          if (hit_f(bi, ia, bj1, ja1)) h1 |= (1ull << i);
          if (hit_f(bi, ia, bj2, ja2)) h2 |= (1ull << i);
          if (hit_f(bi, ia, bj3, ja3)) h3 |= (1ull << i);
        }
        if (j0 < M) hmask[j0] = h0;
        if (j1 < M) hmask[j1] = h1;
        if (j2 < M) hmask[j2] = h2;
        if (j3 < M) hmask[j3] = h3;
      }
    }
    __syncthreads();   // B: hmask ready

    // step 2 (wave 0): serial ballot resolve on precomputed bits
    if (tid < 64) {
      int j = start + tid, g = start >> 6;
      u64 kw = keepmask[g];
      bool alive = (kw >> tid) & 1;
      u64 mask = alive ? (hmask[j] & ((1ull << tid) - 1ull)) : 0ull;
      u64 rem = ~__ballot(alive);
      for (int i = 0; i < 63; ++i) {
        if (!((rem >> i) & 1)) rem |= __ballot((mask >> i) & 1);
        else                   (void)__ballot(0);
      }
      bool kept = alive && !((rem >> tid) & 1);
      u64 km = __ballot(kept);
      if (tid == 0) { keepmask[g] = km; chunk_kept = km; }
    }
    __syncthreads();   // C: chunk_kept + chunk keep word final

    // step 3: cross-chunk suppression; each wave owns aligned 64-j windows
    u64 km = chunk_kept;
    for (int jb = start + 64 + (w << 6); jb < M; jb += 256) {
      int g = jb >> 6;
      u64 kw = keepmask[g];
      if (kw == 0ull) continue;          // wave-uniform
      int j = jb + l;
      bool supp = ((kw >> l) & 1) && (hmask[j < MAXM ? j : 0] & km);
      u64 sb = __ballot(supp);
      if (l == 0 && sb) keepmask[g] = kw & ~sb;
    }
  }
  __syncthreads();

  // --- parallel compaction: first min(total,200) kept, sorted order ---
  if (tid < 16) {
    int acc = 0;
    for (int i = 0; i < tid; ++i) acc += (int)__popcll(keepmask[i]);
    segbase[tid] = acc;
  }
  __syncthreads();
  int total = segbase[15] + (int)__popcll(keepmask[15]);
  for (int s = 0; s < 4; ++s) {
    int seg = (w << 2) + s;
    u64 word = keepmask[seg];
    int p = (seg << 6) + l;
    if ((word >> l) & 1) {
      int rank = segbase[seg] + (int)__popcll(word & ((1ull << l) - 1ull));
      if (rank < MAXKEEP) {
        u64 k = sorted_key[gbase + p];
        u32 sbits = (u32)(k >> 32);
        int n = (int)(0xFFFFFFFFu - (u32)(k & 0xFFFFFFFFull));
        lane_key[(size_t)lane * MAXKEEP + rank] = pack_key(sbits, c * NROI + p, n);
      }
    }
  }
  if (tid == 0) keep_count[lane] = min(total, MAXKEEP);
}

// --- kernel 3: per-batch parallel top-200 (radix-select + bitonic), exact order ---
__global__ __launch_bounds__(256) void merge_kernel(
    const float* __restrict__ roi, const float* __restrict__ deltas,
    const int* __restrict__ keep_count, const u64* __restrict__ lane_key,
    float* __restrict__ out_b, float* __restrict__ out_c, float* __restrict__ out_s) {
  int b = blockIdx.x;
  int tid = threadIdx.x;

  __shared__ int hist[HSIZE];
  __shared__ int csum[256];
  __shared__ int cnts[NCLS];
  __shared__ int tb_sh, scnt_sh;
  __shared__ u64 surv[SCAP];

  for (int i = tid; i < HSIZE; i += 256) hist[i] = 0;
  for (int i = tid; i < NCLS; i += 256) cnts[i] = keep_count[b * NCLS + i];
  if (tid == 0) { tb_sh = 0; scnt_sh = 0; }
  __syncthreads();

  // histogram on top-13 mantissa bits (scores in (0.5,1): exponent constant,
  // so bucket order == score order)
  for (int s = tid; s < NCLS * MAXKEEP; s += 256) {
    int c = s / MAXKEEP, h = s % MAXKEEP;
    if (h < cnts[c]) {
      u64 k = lane_key[((size_t)(b * NCLS + c)) * MAXKEEP + h];
      u32 sb = (u32)(k >> 32);
      atomicAdd(&hist[(sb >> 10) & (HSIZE - 1)], 1);
    }
  }
  __syncthreads();

  // suffix sums; find tb = max bucket with sufsum >= 200 (0 if total < 200)
  int base = tid * 32;
  int psum = 0;
  for (int i = 0; i < 32; ++i) psum += hist[base + i];
  csum[tid] = psum;
  __syncthreads();
  if (tid == 0) {
    int acc = 0;
    for (int t = 255; t >= 0; --t) { acc += csum[t]; csum[t] = acc; }
  }
  __syncthreads();
  int acc = (tid < 255) ? csum[tid + 1] : 0;
  int local_tb = -1;
  for (int i = 31; i >= 0; --i) {
    acc += hist[base + i];
    if (acc >= MAXKEEP && local_tb < 0) local_tb = base + i;
  }
  if (local_tb >= 0) atomicMax(&tb_sh, local_tb);
  __syncthreads();
  int tb = tb_sh;

  // gather survivors (all keys in buckets >= tb; superset of exact top-200)
  for (int s = tid; s < NCLS * MAXKEEP; s += 256) {
    int c = s / MAXKEEP, h = s % MAXKEEP;
    if (h < cnts[c]) {
      u64 k = lane_key[((size_t)(b * NCLS + c)) * MAXKEEP + h];
      u32 sb = (u32)(k >> 32);
      if ((int)((sb >> 10) & (HSIZE - 1)) >= tb) {
        int pos = atomicAdd(&scnt_sh, 1);
        if (pos < SCAP) surv[pos] = k;
      }
    }
  }
  __syncthreads();
  int scnt = min(scnt_sh, SCAP);
  int size = 2;
  while (size < scnt) size <<= 1;
  for (int i = scnt + tid; i < size; i += 256) surv[i] = 0ull;
  __syncthreads();

  // bitonic sort descending by full key (score desc, flat asc)
  for (int k2 = 2; k2 <= size; k2 <<= 1) {
    for (int j = k2 >> 1; j > 0; j >>= 1) {
      for (int i = tid; i < size; i += 256) {
        int ixj = i ^ j;
        if (ixj > i) {
          u64 a = surv[i], bb = surv[ixj];
          bool swp = ((i & k2) == 0) ? (a < bb) : (a > bb);
          if (swp) { surv[i] = bb; surv[ixj] = a; }
        }
      }
      __syncthreads();
    }
  }

  // decode + write top-200 in parallel; zero-fill the rest
  for (int t = tid; t < MAXKEEP; t += 256) {
    size_t ob = ((size_t)b * MAXKEEP + t) * 4;
    if (t < scnt) {
      u64 k = surv[t];
      int flat = 131071 - (int)((k >> 15) & 0x1FFFF);
      int c = flat / NROI;
      int n = (int)((k >> 5) & 0x3FF);
      int row = b * NROI + n;
      float by1, bx1, by2, bx2;
      decode_box(roi + (size_t)row * 4, deltas + ((size_t)row * NCLS + c) * 4,
                 by1, bx1, by2, bx2);
      out_b[ob + 0] = fminf(fmaxf(by1, 0.0f), 1.0f);
      out_b[ob + 1] = fminf(fmaxf(bx1, 0.0f), 1.0f);
      out_b[ob + 2] = fminf(fmaxf(by2, 0.0f), 1.0f);
      out_b[ob + 3] = fminf(fmaxf(bx2, 0.0f), 1.0f);
      out_c[b * MAXKEEP + t] = (float)c;
      out_s[b * MAXKEEP + t] = __uint_as_float((u32)(k >> 32));
    } else {
      out_b[ob + 0] = 0.0f; out_b[ob + 1] = 0.0f;
      out_b[ob + 2] = 0.0f; out_b[ob + 3] = 0.0f;
      out_c[b * MAXKEEP + t] = 0.0f;
      out_s[b * MAXKEEP + t] = 0.0f;
    }
  }
}

extern "C" void kernel_launch(void* const* d_in, const int* in_sizes, int n_in,
                              void* d_out, int out_size, void* d_ws, size_t ws_size,
                              hipStream_t stream) {
  const float* roi    = (const float*)d_in[0];  // [8,1000,4]
  const float* deltas = (const float*)d_in[1];  // [8,1000,324]
  const float* probs  = (const float*)d_in[2];  // [8,1000,81]

  char* ws = (char*)d_ws;
  int* bg         = (int*)(ws);                   // 32000 B
  int* keep_count = (int*)(ws + 32768);           // 2592 B
  u64* lane_key   = (u64*)(ws + 40960);           // 648*200*8 = 1,036,800 B
  u64* sorted_key = (u64*)(ws + 40960 + 1081344); // 648*1024*8 = 5,308,416 B

  float* out_b = (float*)d_out;                 // [8,200,4]
  float* out_c = out_b + NB * MAXKEEP * 4;      // [8,200]
  float* out_s = out_c + NB * MAXKEEP;          // [8,200]

  bg_kernel<<<(NB * NROI + 3) / 4, 256, 0, stream>>>(probs, bg);
  gather_nms_kernel<<<NLANE, 256, 0, stream>>>(roi, deltas, probs, bg,
                                               sorted_key, keep_count, lane_key);
  merge_kernel<<<NB, 256, 0, stream>>>(roi, deltas, keep_count, lane_key,
                                       out_b, out_c, out_s);
}

// Round 6
// 169.292 us; speedup vs baseline: 1.9241x; 1.9241x over previous
//
#include <hip/hip_runtime.h>

#define NROI 1000
#define NCLS 81
#define NB   8
#define NLANE (NB*NCLS)        // 648
#define MAXM 1024
#define MAXKEEP 200
#define SCORE_T 0.5f
#define NT 512
#define NW (NT/64)             // 8 waves
#define HBITS 13
#define HSIZE (1<<HBITS)       // 8192 buckets
#define SCAP 1024

typedef unsigned long long u64;
typedef unsigned int u32;

// --- exact-order helpers (no FMA contraction; must match f32 numpy reference) ---

__device__ __forceinline__ void decode_box(const float* __restrict__ roi,
                                           const float* __restrict__ dl,
                                           float& oy1, float& ox1,
                                           float& oy2, float& ox2) {
#pragma clang fp contract(off)
  float y1 = roi[0], x1 = roi[1], y2 = roi[2], x2 = roi[3];
  float h = y2 - y1;
  float w = x2 - x1;
  float cy = y1 + 0.5f * h;
  float cx = x1 + 0.5f * w;
  float d0 = dl[0] * 0.1f;
  float d1 = dl[1] * 0.1f;
  float d2 = dl[2] * 0.2f;
  float d3 = dl[3] * 0.2f;
  float ncy = d0 * h + cy;
  float ncx = d1 * w + cx;
  float nh = expf(d2) * h;
  float nw = expf(d3) * w;
  oy1 = ncy - 0.5f * nh;
  ox1 = ncx - 0.5f * nw;
  oy2 = ncy + 0.5f * nh;
  ox2 = ncx + 0.5f * nw;
}

__device__ __forceinline__ float area_f(float4 bx) {
#pragma clang fp contract(off)
  return (bx.z - bx.x) * (bx.w - bx.y);
}

// EXACT equivalent of: fl32(inter/den) > 0.5 (round-nearest-even).
// fl(q) > 0.5  <=>  q_real > 0.5 + 2^-25  <=>  inter > (0.5+2^-25)*den,
// and (0.5+2^-25)*den is exact in double (25b x 24b mantissas < 53b).
__device__ __forceinline__ bool hit_f(float4 bi, float ia, float4 bj, float ja) {
#pragma clang fp contract(off)
  float yy1 = fmaxf(bi.x, bj.x);
  float xx1 = fmaxf(bi.y, bj.y);
  float yy2 = fminf(bi.z, bj.z);
  float xx2 = fminf(bi.w, bj.w);
  float ih = fmaxf(yy2 - yy1, 0.0f);
  float iw = fmaxf(xx2 - xx1, 0.0f);
  float inter = ih * iw;
  float den = ia + ja;
  den = den - inter;
  den = den + 1e-8f;
  return (double)inter > (0.5 + 0x1p-25) * (double)den;
}

// key packing: [63:32] score bits, [31:15] (131071-flat) so lower flat wins,
//              [14:5] n (payload only), [4:0] zero. Empty slot = 0.
__device__ __forceinline__ u64 pack_key(u32 sbits, int flat, int n) {
  return ((u64)sbits << 32) | ((u64)(131071 - flat) << 15) | ((u64)n << 5);
}

// --- kernel 1: background rows (argmax over classes == 0), wave per row ---
__global__ __launch_bounds__(256) void bg_kernel(const float* __restrict__ probs,
                                                 int* __restrict__ bg) {
  int row = blockIdx.x * 4 + (threadIdx.x >> 6);
  int lane = threadIdx.x & 63;
  if (row >= NB * NROI) return;
  const float* p = probs + (size_t)row * NCLS;
  float m = -1e30f;
  for (int idx = 1 + lane; idx < NCLS; idx += 64) m = fmaxf(m, p[idx]);
  for (int off = 32; off; off >>= 1) m = fmaxf(m, __shfl_xor(m, off));
  if (lane == 0) bg[row] = (p[0] >= m) ? 1 : 0;  // argmax==0 iff p0 >= all others
}

// --- kernel 2 (fused): gather + rank-sort + decode + reg-cached greedy NMS ---
__global__ __launch_bounds__(NT) void gather_nms_kernel(
    const float* __restrict__ roi, const float* __restrict__ deltas,
    const float* __restrict__ probs, const int* __restrict__ bg,
    int* __restrict__ keep_count, u64* __restrict__ lane_key) {
  int lane = blockIdx.x;               // 0..647
  int b = lane / NCLS, c = lane % NCLS;
  int tid = threadIdx.x;
  int w = tid >> 6, l = tid & 63;

  // smem layout: [0,16K) sbox (alias: skeyU in [0,8K), dead after sort)
  //              [16K,24K) hmask; [24K,32K) skey (sorted, live to the end)
  //              [32K,36K) sarea
  __shared__ alignas(16) char smem[36864];
  float4* sbox  = (float4*)smem;
  u64*    skeyU = (u64*)smem;
  u64*    hmask = (u64*)(smem + 16384);
  u64*    skey  = (u64*)(smem + 24576);
  float*  sarea = (float*)(smem + 32768);
  __shared__ u64 keepmask[16];
  __shared__ u64 chunk_kept;
  __shared__ int scount, segbase[16];

  if (tid == 0) scount = 0;
  __syncthreads();

  // --- gather: score > 0.5 && !bg (ballot-aggregated append; M <= 1000) ---
  for (int base_n = 0; base_n < NROI; base_n += NT) {
    int n = base_n + tid;
    bool cand = false;
    float s = 0.0f;
    if (n < NROI) {
      int row = b * NROI + n;
      s = probs[(size_t)row * NCLS + c];
      cand = (s > SCORE_T) && (bg[row] == 0);
    }
    u64 bal = __ballot(cand);
    int wbase = 0;
    if (l == 0) wbase = atomicAdd(&scount, (int)__popcll(bal));
    wbase = __shfl(wbase, 0);
    if (cand) {
      int off = (int)__popcll(bal & ((1ull << l) - 1ull));
      skeyU[wbase + off] = ((u64)__float_as_uint(s) << 32) | (u64)(0xFFFFFFFFu - (u32)n);
    }
  }
  __syncthreads();
  int M = scount;          // <= 1000

  // --- rank sort: keys unique -> rank is a permutation (2 keys/thread) ---
  u64 k0 = (tid      < M) ? skeyU[tid]      : 0ull;
  u64 k1 = (tid + NT < M) ? skeyU[tid + NT] : 0ull;
  int r0 = 0, r1 = 0;
  for (int q = 0; q < M; ++q) {        // broadcast LDS read, conflict-free
    u64 kq = skeyU[q];
    r0 += kq > k0;
    r1 += kq > k1;
  }
  if (tid < 16) {                       // init keep bitmask: bits p < M set
    int rem = M - (tid << 6);
    keepmask[tid] = (rem >= 64) ? ~0ull : ((rem <= 0) ? 0ull : ((1ull << rem) - 1ull));
  }
  if (tid      < M) skey[r0] = k0;
  if (tid + NT < M) skey[r1] = k1;
  __syncthreads();   // all skeyU reads done; skey ready

  // --- decode sorted candidates into sbox (overwrites dead skeyU region) ---
  for (int p = tid; p < M; p += NT) {
    u64 k = skey[p];
    u32 n = 0xFFFFFFFFu - (u32)(k & 0xFFFFFFFFull);
    int row = b * NROI + (int)n;
    float by1, bx1, by2, bx2;
    decode_box(roi + (size_t)row * 4, deltas + ((size_t)row * NCLS + c) * 4,
               by1, bx1, by2, bx2);
    float4 bx = make_float4(by1, bx1, by2, bx2);
    sbox[p] = bx;
    sarea[p] = area_f(bx);
  }

  // --- chunked greedy NMS: reg-cached chunk boxes + ballot masks ---
  int nchunks = (M + 63) >> 6;
  for (int ck = 0; ck < nchunks; ++ck) {
    int start = ck << 6;
    __syncthreads();   // A: decode done / prev step3 done; hmask free

    // every wave's lane l caches chunk box start+l (garbage beyond M: masked)
    float4 bi = sbox[start + l];
    float ia = sarea[start + l];

    // step 1: wave-parallel hit masks; 8 waves split the j range
    for (int j = start + w; j < M; j += NW) {
      float4 bj = sbox[j];             // broadcast (same addr all lanes)
      float ja = sarea[j];
      bool h = hit_f(bi, ia, bj, ja);
      u64 bal = __ballot(h);
      if (l == 0) hmask[j] = bal;
    }
    __syncthreads();   // B: hmask ready

    // step 2 (wave 0): serial ballot resolve on precomputed bits
    if (tid < 64) {
      u64 kw = keepmask[ck];
      bool alive = (kw >> l) & 1;
      u64 mask = alive ? (hmask[start + l] & ((1ull << l) - 1ull)) : 0ull;
      u64 rem = ~__ballot(alive);
      for (int i = 0; i < 63; ++i) {
        if (!((rem >> i) & 1)) rem |= __ballot((mask >> i) & 1);
        else                   (void)__ballot(0);
      }
      bool kept = alive && !((rem >> l) & 1);
      u64 km = __ballot(kept);
      if (l == 0) { keepmask[ck] = km; chunk_kept = km; }
    }
    __syncthreads();   // C: chunk_kept + chunk keep word final

    // step 3: cross-chunk suppression; one 64-j group per wave round-robin
    u64 km = chunk_kept;
    for (int g = ck + 1 + w; g < nchunks; g += NW) {
      u64 kw = keepmask[g];
      if (kw == 0ull) continue;        // wave-uniform
      int j = (g << 6) + l;            // kw bit l set implies j < M
      bool supp = ((kw >> l) & 1) && (hmask[j] & km);
      u64 sb = __ballot(supp);
      if (l == 0 && sb) keepmask[g] = kw & ~sb;
    }
  }
  __syncthreads();

  // --- parallel compaction: first min(total,200) kept, sorted order ---
  if (tid < 16) {
    int acc = 0;
    for (int i = 0; i < tid; ++i) acc += (int)__popcll(keepmask[i]);
    segbase[tid] = acc;
  }
  __syncthreads();
  int total = segbase[15] + (int)__popcll(keepmask[15]);
  for (int s = 0; s < 2; ++s) {
    int seg = (w << 1) + s;
    u64 word = keepmask[seg];
    int p = (seg << 6) + l;
    if ((word >> l) & 1) {
      int rank = segbase[seg] + (int)__popcll(word & ((1ull << l) - 1ull));
      if (rank < MAXKEEP) {
        u64 k = skey[p];
        u32 sbits = (u32)(k >> 32);
        int n = (int)(0xFFFFFFFFu - (u32)(k & 0xFFFFFFFFull));
        lane_key[(size_t)lane * MAXKEEP + rank] = pack_key(sbits, c * NROI + p, n);
      }
    }
  }
  if (tid == 0) keep_count[lane] = min(total, MAXKEEP);
}

// --- kernel 3: per-batch parallel top-200 (radix-select + bitonic), exact order ---
__global__ __launch_bounds__(512) void merge_kernel(
    const float* __restrict__ roi, const float* __restrict__ deltas,
    const int* __restrict__ keep_count, const u64* __restrict__ lane_key,
    float* __restrict__ out_b, float* __restrict__ out_c, float* __restrict__ out_s) {
  int b = blockIdx.x;
  int tid = threadIdx.x;

  __shared__ int hist[HSIZE];
  __shared__ int csum[256];
  __shared__ int cnts[NCLS];
  __shared__ int tb_sh, scnt_sh;
  __shared__ u64 surv[SCAP];

  for (int i = tid; i < HSIZE; i += 512) hist[i] = 0;
  for (int i = tid; i < NCLS; i += 512) cnts[i] = keep_count[b * NCLS + i];
  if (tid == 0) { tb_sh = 0; scnt_sh = 0; }
  __syncthreads();

  // histogram on top-13 mantissa bits (scores in (0.5,1): exponent constant,
  // so bucket order == score order)
  for (int s = tid; s < NCLS * MAXKEEP; s += 512) {
    int c = s / MAXKEEP, h = s % MAXKEEP;
    if (h < cnts[c]) {
      u64 k = lane_key[((size_t)(b * NCLS + c)) * MAXKEEP + h];
      u32 sb = (u32)(k >> 32);
      atomicAdd(&hist[(sb >> 10) & (HSIZE - 1)], 1);
    }
  }
  __syncthreads();

  // suffix sums; find tb = max bucket with sufsum >= 200 (0 if total < 200)
  int base = tid * 32;
  if (tid < 256) {
    int psum = 0;
    for (int i = 0; i < 32; ++i) psum += hist[base + i];
    csum[tid] = psum;
  }
  __syncthreads();
  if (tid == 0) {
    int acc = 0;
    for (int t = 255; t >= 0; --t) { acc += csum[t]; csum[t] = acc; }
  }
  __syncthreads();
  if (tid < 256) {
    int acc = (tid < 255) ? csum[tid + 1] : 0;
    int local_tb = -1;
    for (int i = 31; i >= 0; --i) {
      acc += hist[base + i];
      if (acc >= MAXKEEP && local_tb < 0) local_tb = base + i;
    }
    if (local_tb >= 0) atomicMax(&tb_sh, local_tb);
  }
  __syncthreads();
  int tb = tb_sh;

  // gather survivors (all keys in buckets >= tb; superset of exact top-200)
  for (int s = tid; s < NCLS * MAXKEEP; s += 512) {
    int c = s / MAXKEEP, h = s % MAXKEEP;
    if (h < cnts[c]) {
      u64 k = lane_key[((size_t)(b * NCLS + c)) * MAXKEEP + h];
      u32 sb = (u32)(k >> 32);
      if ((int)((sb >> 10) & (HSIZE - 1)) >= tb) {
        int pos = atomicAdd(&scnt_sh, 1);
        if (pos < SCAP) surv[pos] = k;
      }
    }
  }
  __syncthreads();
  int scnt = min(scnt_sh, SCAP);
  int size = 2;
  while (size < scnt) size <<= 1;
  for (int i = scnt + tid; i < size; i += 512) surv[i] = 0ull;
  __syncthreads();

  // bitonic sort descending by full key (score desc, flat asc)
  for (int k2 = 2; k2 <= size; k2 <<= 1) {
    for (int j = k2 >> 1; j > 0; j >>= 1) {
      for (int i = tid; i < size; i += 512) {
        int ixj = i ^ j;
        if (ixj > i) {
          u64 a = surv[i], bb = surv[ixj];
          bool swp = ((i & k2) == 0) ? (a < bb) : (a > bb);
          if (swp) { surv[i] = bb; surv[ixj] = a; }
        }
      }
      __syncthreads();
    }
  }

  // decode + write top-200 in parallel; zero-fill the rest
  for (int t = tid; t < MAXKEEP; t += 512) {
    size_t ob = ((size_t)b * MAXKEEP + t) * 4;
    if (t < scnt) {
      u64 k = surv[t];
      int flat = 131071 - (int)((k >> 15) & 0x1FFFF);
      int c = flat / NROI;
      int n = (int)((k >> 5) & 0x3FF);
      int row = b * NROI + n;
      float by1, bx1, by2, bx2;
      decode_box(roi + (size_t)row * 4, deltas + ((size_t)row * NCLS + c) * 4,
                 by1, bx1, by2, bx2);
      out_b[ob + 0] = fminf(fmaxf(by1, 0.0f), 1.0f);
      out_b[ob + 1] = fminf(fmaxf(bx1, 0.0f), 1.0f);
      out_b[ob + 2] = fminf(fmaxf(by2, 0.0f), 1.0f);
      out_b[ob + 3] = fminf(fmaxf(bx2, 0.0f), 1.0f);
      out_c[b * MAXKEEP + t] = (float)c;
      out_s[b * MAXKEEP + t] = __uint_as_float((u32)(k >> 32));
    } else {
      out_b[ob + 0] = 0.0f; out_b[ob + 1] = 0.0f;
      out_b[ob + 2] = 0.0f; out_b[ob + 3] = 0.0f;
      out_c[b * MAXKEEP + t] = 0.0f;
      out_s[b * MAXKEEP + t] = 0.0f;
    }
  }
}

extern "C" void kernel_launch(void* const* d_in, const int* in_sizes, int n_in,
                              void* d_out, int out_size, void* d_ws, size_t ws_size,
                              hipStream_t stream) {
  const float* roi    = (const float*)d_in[0];  // [8,1000,4]
  const float* deltas = (const float*)d_in[1];  // [8,1000,324]
  const float* probs  = (const float*)d_in[2];  // [8,1000,81]

  char* ws = (char*)d_ws;
  int* bg         = (int*)(ws);                   // 32000 B
  int* keep_count = (int*)(ws + 32768);           // 2592 B
  u64* lane_key   = (u64*)(ws + 40960);           // 648*200*8 = 1,036,800 B

  float* out_b = (float*)d_out;                 // [8,200,4]
  float* out_c = out_b + NB * MAXKEEP * 4;      // [8,200]
  float* out_s = out_c + NB * MAXKEEP;          // [8,200]

  bg_kernel<<<(NB * NROI + 3) / 4, 256, 0, stream>>>(probs, bg);
  gather_nms_kernel<<<NLANE, NT, 0, stream>>>(roi, deltas, probs, bg,
                                              keep_count, lane_key);
  merge_kernel<<<NB, 512, 0, stream>>>(roi, deltas, keep_count, lane_key,
                                       out_b, out_c, out_s);
}

// Round 7
// 166.609 us; speedup vs baseline: 1.9551x; 1.0161x over previous
//
#include <hip/hip_runtime.h>

#define NROI 1000
#define NCLS 81
#define NB   8
#define NLANE (NB*NCLS)        // 648 = 8 XCDs * 81
#define MAXM 1024
#define MAXKEEP 200
#define SCORE_T 0.5f
#define NT 512
#define NW (NT/64)             // 8 waves
#define HBITS 13
#define HSIZE (1<<HBITS)       // 8192 buckets
#define SCAP 1024

typedef unsigned long long u64;
typedef unsigned int u32;

// --- exact-order helpers (no FMA contraction; must match f32 numpy reference) ---

__device__ __forceinline__ void decode_box(const float* __restrict__ roi,
                                           const float* __restrict__ dl,
                                           float& oy1, float& ox1,
                                           float& oy2, float& ox2) {
#pragma clang fp contract(off)
  float y1 = roi[0], x1 = roi[1], y2 = roi[2], x2 = roi[3];
  float h = y2 - y1;
  float w = x2 - x1;
  float cy = y1 + 0.5f * h;
  float cx = x1 + 0.5f * w;
  float d0 = dl[0] * 0.1f;
  float d1 = dl[1] * 0.1f;
  float d2 = dl[2] * 0.2f;
  float d3 = dl[3] * 0.2f;
  float ncy = d0 * h + cy;
  float ncx = d1 * w + cx;
  float nh = expf(d2) * h;
  float nw = expf(d3) * w;
  oy1 = ncy - 0.5f * nh;
  ox1 = ncx - 0.5f * nw;
  oy2 = ncy + 0.5f * nh;
  ox2 = ncx + 0.5f * nw;
}

__device__ __forceinline__ float area_f(float4 bx) {
#pragma clang fp contract(off)
  return (bx.z - bx.x) * (bx.w - bx.y);
}

// EXACT equivalent of: fl32(inter/den) > 0.5 (round-nearest-even), den>0:
//   fl(q)>0.5 <=> q > 0.5+2^-25 <=> 2*inter > den*(1+2^-24)  (reals).
// 2*inter is an exact float; den*2^-24 < ulp(den) strictly, so den*(1+2^-24)
// lies strictly between den and succ(den)  =>  test == (2*inter > den) in f32.
__device__ __forceinline__ bool hit_f(float4 bi, float ia, float4 bj, float ja) {
#pragma clang fp contract(off)
  float yy1 = fmaxf(bi.x, bj.x);
  float xx1 = fmaxf(bi.y, bj.y);
  float yy2 = fminf(bi.z, bj.z);
  float xx2 = fminf(bi.w, bj.w);
  float ih = fmaxf(yy2 - yy1, 0.0f);
  float iw = fmaxf(xx2 - xx1, 0.0f);
  float inter = ih * iw;
  float den = ia + ja;
  den = den - inter;
  den = den + 1e-8f;
  return (inter + inter) > den;
}

// key packing: [63:32] score bits, [31:15] (131071-flat) so lower flat wins,
//              [14:5] n (payload only), [4:0] zero. Empty slot = 0.
__device__ __forceinline__ u64 pack_key(u32 sbits, int flat, int n) {
  return ((u64)sbits << 32) | ((u64)(131071 - flat) << 15) | ((u64)n << 5);
}

// --- kernel 1: background rows (argmax over classes == 0), wave per row ---
__global__ __launch_bounds__(256) void bg_kernel(const float* __restrict__ probs,
                                                 int* __restrict__ bg) {
  int row = blockIdx.x * 4 + (threadIdx.x >> 6);
  int lane = threadIdx.x & 63;
  if (row >= NB * NROI) return;
  const float* p = probs + (size_t)row * NCLS;
  float m = -1e30f;
  for (int idx = 1 + lane; idx < NCLS; idx += 64) m = fmaxf(m, p[idx]);
  for (int off = 32; off; off >>= 1) m = fmaxf(m, __shfl_xor(m, off));
  if (lane == 0) bg[row] = (p[0] >= m) ? 1 : 0;  // argmax==0 iff p0 >= all others
}

// --- kernel 2 (fused): gather + rank-sort + decode + reg-cached greedy NMS ---
__global__ __launch_bounds__(NT) void gather_nms_kernel(
    const float* __restrict__ roi, const float* __restrict__ deltas,
    const float* __restrict__ probs, const int* __restrict__ bg,
    int* __restrict__ keep_count, u64* __restrict__ lane_key,
    int* __restrict__ bhist) {
  // XCD swizzle: 648 = 8*81; dispatch idx%8 = XCD -> XCD x owns batch x entirely
  int lane = (blockIdx.x % 8) * NCLS + blockIdx.x / 8;
  int b = lane / NCLS, c = lane % NCLS;
  int tid = threadIdx.x;
  int w = tid >> 6, l = tid & 63;

  // smem layout: [0,16K) sbox (alias: skeyU in [0,8K), dead after sort)
  //              [16K,24K) hmask; [24K,32K) skey (sorted, live to the end)
  //              [32K,36K) sarea
  __shared__ alignas(16) char smem[36864];
  float4* sbox  = (float4*)smem;
  u64*    skeyU = (u64*)smem;
  u64*    hmask = (u64*)(smem + 16384);
  u64*    skey  = (u64*)(smem + 24576);
  float*  sarea = (float*)(smem + 32768);
  __shared__ u64 keepmask[16];
  __shared__ u64 chunk_kept;
  __shared__ int scount, segbase[16];

  if (tid == 0) scount = 0;
  __syncthreads();

  // --- gather: score > 0.5 && !bg (ballot-aggregated append; M <= 1000) ---
  for (int base_n = 0; base_n < NROI; base_n += NT) {
    int n = base_n + tid;
    bool cand = false;
    float s = 0.0f;
    if (n < NROI) {
      int row = b * NROI + n;
      s = probs[(size_t)row * NCLS + c];
      cand = (s > SCORE_T) && (bg[row] == 0);
    }
    u64 bal = __ballot(cand);
    int wbase = 0;
    if (l == 0) wbase = atomicAdd(&scount, (int)__popcll(bal));
    wbase = __shfl(wbase, 0);
    if (cand) {
      int off = (int)__popcll(bal & ((1ull << l) - 1ull));
      skeyU[wbase + off] = ((u64)__float_as_uint(s) << 32) | (u64)(0xFFFFFFFFu - (u32)n);
    }
  }
  __syncthreads();
  int M = scount;          // <= 1000

  // --- rank sort: keys unique -> rank is a permutation ---
  if (M <= NT) {           // block-uniform fast path: 1 key/thread
    u64 k0 = (tid < M) ? skeyU[tid] : 0ull;
    int r0 = 0;
    for (int q = 0; q < M; ++q) r0 += skeyU[q] > k0;
    if (tid < 16) {
      int rem = M - (tid << 6);
      keepmask[tid] = (rem >= 64) ? ~0ull : ((rem <= 0) ? 0ull : ((1ull << rem) - 1ull));
    }
    if (tid < M) skey[r0] = k0;
  } else {                 // 2 keys/thread
    u64 k0 = skeyU[tid];
    u64 k1 = (tid + NT < M) ? skeyU[tid + NT] : 0ull;
    int r0 = 0, r1 = 0;
    for (int q = 0; q < M; ++q) {
      u64 kq = skeyU[q];
      r0 += kq > k0;
      r1 += kq > k1;
    }
    if (tid < 16) {
      int rem = M - (tid << 6);
      keepmask[tid] = (rem >= 64) ? ~0ull : ((rem <= 0) ? 0ull : ((1ull << rem) - 1ull));
    }
    skey[r0] = k0;
    if (tid + NT < M) skey[r1] = k1;
  }
  __syncthreads();   // all skeyU reads done; skey ready

  // --- decode sorted candidates into sbox (overwrites dead skeyU region) ---
  for (int p = tid; p < M; p += NT) {
    u64 k = skey[p];
    u32 n = 0xFFFFFFFFu - (u32)(k & 0xFFFFFFFFull);
    int row = b * NROI + (int)n;
    float by1, bx1, by2, bx2;
    decode_box(roi + (size_t)row * 4, deltas + ((size_t)row * NCLS + c) * 4,
               by1, bx1, by2, bx2);
    float4 bx = make_float4(by1, bx1, by2, bx2);
    sbox[p] = bx;
    sarea[p] = area_f(bx);
  }

  // --- chunked greedy NMS: reg-cached chunk boxes + ballot masks ---
  int nchunks = (M + 63) >> 6;
  for (int ck = 0; ck < nchunks; ++ck) {
    int start = ck << 6;
    __syncthreads();   // A: decode done / prev step3 done; hmask free

    // every wave's lane l caches chunk box start+l (garbage beyond M: masked)
    float4 bi = sbox[start + l];
    float ia = sarea[start + l];

    // step 1: wave-parallel hit masks; 8 waves split j; skip dead j (uniform)
    for (int j = start + w; j < M; j += NW) {
      if (!((keepmask[j >> 6] >> (j & 63)) & 1)) continue;  // wave-uniform
      float4 bj = sbox[j];             // broadcast (same addr all lanes)
      float ja = sarea[j];
      bool h = hit_f(bi, ia, bj, ja);
      u64 bal = __ballot(h);
      if (l == 0) hmask[j] = bal;
    }
    __syncthreads();   // B: hmask ready

    // step 2 (wave 0): serial ballot resolve on precomputed bits
    if (tid < 64) {
      u64 kw = keepmask[ck];
      bool alive = (kw >> l) & 1;
      u64 mask = alive ? (hmask[start + l] & ((1ull << l) - 1ull)) : 0ull;
      u64 rem = ~__ballot(alive);
      for (int i = 0; i < 63; ++i) {
        if (!((rem >> i) & 1)) rem |= __ballot((mask >> i) & 1);  // uniform branch
      }
      bool kept = alive && !((rem >> l) & 1);
      u64 km = __ballot(kept);
      if (l == 0) { keepmask[ck] = km; chunk_kept = km; }
    }
    __syncthreads();   // C: chunk_kept + chunk keep word final

    // step 3: cross-chunk suppression; one 64-j group per wave round-robin
    u64 km = chunk_kept;
    for (int g = ck + 1 + w; g < nchunks; g += NW) {
      u64 kw = keepmask[g];
      if (kw == 0ull) continue;        // wave-uniform
      int j = (g << 6) + l;            // kw bit l set implies j < M
      bool supp = ((kw >> l) & 1) && (hmask[j] & km);
      u64 sb = __ballot(supp);
      if (l == 0 && sb) keepmask[g] = kw & ~sb;
    }
  }
  __syncthreads();

  // --- parallel compaction + fused per-batch histogram ---
  if (tid < 16) {
    int acc = 0;
    for (int i = 0; i < tid; ++i) acc += (int)__popcll(keepmask[i]);
    segbase[tid] = acc;
  }
  __syncthreads();
  int total = segbase[15] + (int)__popcll(keepmask[15]);
  for (int s = 0; s < 2; ++s) {
    int seg = (w << 1) + s;
    u64 word = keepmask[seg];
    int p = (seg << 6) + l;
    if ((word >> l) & 1) {
      int rank = segbase[seg] + (int)__popcll(word & ((1ull << l) - 1ull));
      if (rank < MAXKEEP) {
        u64 k = skey[p];
        u32 sbits = (u32)(k >> 32);
        int n = (int)(0xFFFFFFFFu - (u32)(k & 0xFFFFFFFFull));
        lane_key[(size_t)lane * MAXKEEP + rank] = pack_key(sbits, c * NROI + p, n);
        atomicAdd(&bhist[b * HSIZE + (int)((sbits >> 10) & (HSIZE - 1))], 1);
      }
    }
  }
  if (tid == 0) keep_count[lane] = min(total, MAXKEEP);
}

// --- kernel 3: per-batch parallel top-200 (radix-select + bitonic), exact order ---
__global__ __launch_bounds__(512) void merge_kernel(
    const float* __restrict__ roi, const float* __restrict__ deltas,
    const int* __restrict__ keep_count, const u64* __restrict__ lane_key,
    const int* __restrict__ bhist,
    float* __restrict__ out_b, float* __restrict__ out_c, float* __restrict__ out_s) {
  int b = blockIdx.x;    // 8 blocks; idx%8 = XCD that produced batch b's keys
  int tid = threadIdx.x;

  __shared__ int hist[HSIZE];
  __shared__ int csum[256];
  __shared__ int cnts[NCLS];
  __shared__ int tb_sh, scnt_sh;
  __shared__ u64 surv[SCAP];

  for (int i = tid; i < HSIZE; i += 512) hist[i] = bhist[b * HSIZE + i];
  for (int i = tid; i < NCLS; i += 512) cnts[i] = keep_count[b * NCLS + i];
  if (tid == 0) { tb_sh = 0; scnt_sh = 0; }
  __syncthreads();

  // suffix sums; find tb = max bucket with sufsum >= 200 (0 if total < 200)
  int base = tid * 32;
  if (tid < 256) {
    int psum = 0;
    for (int i = 0; i < 32; ++i) psum += hist[base + i];
    csum[tid] = psum;
  }
  __syncthreads();
  if (tid == 0) {
    int acc = 0;
    for (int t = 255; t >= 0; --t) { acc += csum[t]; csum[t] = acc; }
  }
  __syncthreads();
  if (tid < 256) {
    int acc = (tid < 255) ? csum[tid + 1] : 0;
    int local_tb = -1;
    for (int i = 31; i >= 0; --i) {
      acc += hist[base + i];
      if (acc >= MAXKEEP && local_tb < 0) local_tb = base + i;
    }
    if (local_tb >= 0) atomicMax(&tb_sh, local_tb);
  }
  __syncthreads();
  int tb = tb_sh;

  // gather survivors (all keys in buckets >= tb; superset of exact top-200)
  for (int s = tid; s < NCLS * MAXKEEP; s += 512) {
    int c = s / MAXKEEP, h = s % MAXKEEP;
    if (h < cnts[c]) {
      u64 k = lane_key[((size_t)(b * NCLS + c)) * MAXKEEP + h];
      u32 sb = (u32)(k >> 32);
      if ((int)((sb >> 10) & (HSIZE - 1)) >= tb) {
        int pos = atomicAdd(&scnt_sh, 1);
        if (pos < SCAP) surv[pos] = k;
      }
    }
  }
  __syncthreads();
  int scnt = min(scnt_sh, SCAP);
  int size = 2;
  while (size < scnt) size <<= 1;
  for (int i = scnt + tid; i < size; i += 512) surv[i] = 0ull;
  __syncthreads();

  // bitonic sort descending by full key (score desc, flat asc)
  for (int k2 = 2; k2 <= size; k2 <<= 1) {
    for (int j = k2 >> 1; j > 0; j >>= 1) {
      for (int i = tid; i < size; i += 512) {
        int ixj = i ^ j;
        if (ixj > i) {
          u64 a = surv[i], bb = surv[ixj];
          bool swp = ((i & k2) == 0) ? (a < bb) : (a > bb);
          if (swp) { surv[i] = bb; surv[ixj] = a; }
        }
      }
      __syncthreads();
    }
  }

  // decode + write top-200 in parallel; zero-fill the rest
  for (int t = tid; t < MAXKEEP; t += 512) {
    size_t ob = ((size_t)b * MAXKEEP + t) * 4;
    if (t < scnt) {
      u64 k = surv[t];
      int flat = 131071 - (int)((k >> 15) & 0x1FFFF);
      int c = flat / NROI;
      int n = (int)((k >> 5) & 0x3FF);
      int row = b * NROI + n;
      float by1, bx1, by2, bx2;
      decode_box(roi + (size_t)row * 4, deltas + ((size_t)row * NCLS + c) * 4,
                 by1, bx1, by2, bx2);
      out_b[ob + 0] = fminf(fmaxf(by1, 0.0f), 1.0f);
      out_b[ob + 1] = fminf(fmaxf(bx1, 0.0f), 1.0f);
      out_b[ob + 2] = fminf(fmaxf(by2, 0.0f), 1.0f);
      out_b[ob + 3] = fminf(fmaxf(bx2, 0.0f), 1.0f);
      out_c[b * MAXKEEP + t] = (float)c;
      out_s[b * MAXKEEP + t] = __uint_as_float((u32)(k >> 32));
    } else {
      out_b[ob + 0] = 0.0f; out_b[ob + 1] = 0.0f;
      out_b[ob + 2] = 0.0f; out_b[ob + 3] = 0.0f;
      out_c[b * MAXKEEP + t] = 0.0f;
      out_s[b * MAXKEEP + t] = 0.0f;
    }
  }
}

extern "C" void kernel_launch(void* const* d_in, const int* in_sizes, int n_in,
                              void* d_out, int out_size, void* d_ws, size_t ws_size,
                              hipStream_t stream) {
  const float* roi    = (const float*)d_in[0];  // [8,1000,4]
  const float* deltas = (const float*)d_in[1];  // [8,1000,324]
  const float* probs  = (const float*)d_in[2];  // [8,1000,81]

  char* ws = (char*)d_ws;
  int* bg         = (int*)(ws);                   // 32000 B
  int* keep_count = (int*)(ws + 32768);           // 2592 B
  int* bhist      = (int*)(ws + 40960);           // 8*8192*4 = 262144 B
  u64* lane_key   = (u64*)(ws + 40960 + 262144);  // 648*200*8 = 1,036,800 B

  float* out_b = (float*)d_out;                 // [8,200,4]
  float* out_c = out_b + NB * MAXKEEP * 4;      // [8,200]
  float* out_s = out_c + NB * MAXKEEP;          // [8,200]

  hipMemsetAsync(bhist, 0, NB * HSIZE * sizeof(int), stream);
  bg_kernel<<<(NB * NROI + 3) / 4, 256, 0, stream>>>(probs, bg);
  gather_nms_kernel<<<NLANE, NT, 0, stream>>>(roi, deltas, probs, bg,
                                              keep_count, lane_key, bhist);
  merge_kernel<<<NB, 512, 0, stream>>>(roi, deltas, keep_count, lane_key, bhist,
                                       out_b, out_c, out_s);
}